// Round 7
// baseline (229.421 us; speedup 1.0000x reference)
//
#include <hip/hip_runtime.h>
#include <cfloat>

#define BB 32
#define AA 8400
#define GG 40
#define NC 80
#define NO 85
#define CAP 2048    // >= geometric bound ~27 anchors/gt * 40 gts = 1080
#define CAPW 13312  // >= 1280 gts * dk_max 10 = 12800
#define POISON 0xAAAAAAAAu
#define K4GRID 104  // fixed: defines the exact phase-4 partial-sum grouping

typedef unsigned long long ull;
#define U64MAX 0xFFFFFFFFFFFFFFFFull

// ---------- deterministic helpers: explicit _rn ops (no FMA contraction) so every
// call site produces bitwise-identical values ----------

__device__ inline bool dev_in(float gx, float gy, float xc, float yc, float r)
{
    float dl = __fsub_rn(xc, __fsub_rn(gx, r));
    float dr = __fsub_rn(__fadd_rn(gx, r), xc);
    float dt = __fsub_rn(yc, __fsub_rn(gy, r));
    float db = __fsub_rn(__fadd_rn(gy, r), yc);
    return fminf(fminf(dl, dr), fminf(dt, db)) > 0.0f;
}

// class-cost term, EXACT op sequence formerly used when materializing clsterm:
//   term = 0.5*log(x*obj) - log(1 - sqrt(x*obj));  ct = nsl - term
__device__ inline float cls_ct(float x, float obj, float nsl)
{
    float mm = __fmul_rn(x, obj);
    float pp = __fsqrt_rn(mm);
    float term = __fsub_rn(__fmul_rn(0.5f, __logf(mm)), __logf(__fsub_rn(1.0f, pp)));
    return __fsub_rn(nsl, term);
}

__device__ inline float2 cost_iou(float gx, float gy, float gw, float gh,
                                  float px, float py, float pw, float ph,
                                  float xc, float yc, float r,
                                  float ct, float fg)
{
    bool in = dev_in(gx, gy, xc, yc, r);
    float gw2 = __fmul_rn(gw, 0.5f), gh2 = __fmul_rn(gh, 0.5f);
    float pw2 = __fmul_rn(pw, 0.5f), ph2 = __fmul_rn(ph, 0.5f);
    float tlx = fmaxf(__fsub_rn(gx, gw2), __fsub_rn(px, pw2));
    float tly = fmaxf(__fsub_rn(gy, gh2), __fsub_rn(py, ph2));
    float brx = fminf(__fadd_rn(gx, gw2), __fadd_rn(px, pw2));
    float bry = fminf(__fadd_rn(gy, gh2), __fadd_rn(py, ph2));
    float en = (tlx < brx && tly < bry) ? 1.0f : 0.0f;
    float ai = __fmul_rn(__fmul_rn(__fsub_rn(brx, tlx), __fsub_rn(bry, tly)), en);
    float ag = __fmul_rn(gw, gh);
    float ap = __fmul_rn(pw, ph);
    float iou = ai / __fsub_rn(__fadd_rn(ag, ap), ai);
    iou = (fg != 0.0f) ? iou : 0.0f;
    float icost = -__logf(__fadd_rn(iou, 1e-8f));
    float cost = __fadd_rn(__fadd_rn(ct, __fmul_rn(3.0f, icost)), in ? 0.0f : 1000000.0f);
    cost = (fg != 0.0f) ? cost : 1000000000.0f;
    return make_float2(cost, iou);
}

__device__ inline float softplus_bce(float x)
{
    return fmaxf(x, 0.0f) + __logf(1.0f + __expf(-fabsf(x)));
}

__device__ inline float wave_sum(float v)
{
#pragma unroll
    for (int o = 32; o > 0; o >>= 1) v += __shfl_down(v, o, 64);
    return v;
}

__device__ inline ull wave_min_u64(ull v)
{
#pragma unroll
    for (int o = 1; o < 64; o <<= 1) {
        ull w = (ull)__shfl_xor((long long)v, o, 64);
        v = w < v ? w : v;
    }
    return v;
}

__device__ inline float wave_max_f(float v)
{
#pragma unroll
    for (int o = 1; o < 64; o <<= 1) v = fmaxf(v, __shfl_xor(v, o, 64));
    return v;
}

// ctrl layout (ints): [0..7]=acc(float), [8..39]=cnt[32], [40]=wlcnt, [41]=fin

// =====================================================================
// K1: fg compaction + per-anchor terms, SYNCLESS phase 2, NO clsterm.
// Phase 1: fg-test this block's 256 anchors, compact into lloc, atomic
//   base into cnt[b].
// Phase 2: one 4-lane group owns one row; lane q computes classes
//   q*20..q*20+19 (same serial order as before); partials combined
//   left-to-right via 4 shfls -> bitwise-identical s1t/s2t/nsl.
//   Outputs per fg anchor: alist, blist, glist, misc=(s2t, obj, nsl, 0).
// =====================================================================
__global__ __launch_bounds__(256) void k1_fgcls(
    const float* __restrict__ outputs, const float* __restrict__ labels,
    const float* __restrict__ xs_, const float* __restrict__ ys_, const float* __restrict__ st_,
    int* __restrict__ ctrl, int* __restrict__ matchcnt, int* __restrict__ alist,
    float4* __restrict__ blist, float4* __restrict__ glist,
    float4* __restrict__ misc)
{
    __shared__ float lgt[GG * 5];
    __shared__ int   lloc[256];
    __shared__ int   scnt[2];          // lcnt, base

    int b = blockIdx.y;
    int tid = threadIdx.x, w = tid >> 6, ln = tid & 63;
    int* cnt = ctrl + 8;

    // poison->0 init: 1 CAS/block on this image's counter; block(0,0) covers ctrl[0..47]
    if (tid == 0) atomicCAS((unsigned*)&cnt[b], POISON, 0u);
    if (blockIdx.x == 0 && b == 0 && tid < 48) atomicCAS((unsigned*)&ctrl[tid], POISON, 0u);
    if (tid == 0) scnt[0] = 0;

    int nb  = gridDim.x * gridDim.y;
    int bid = b * gridDim.x + blockIdx.x;
    for (int i = bid * 256 + tid; i < BB * AA; i += nb * 256) matchcnt[i] = 0;

    for (int i = tid; i < GG * 5; i += 256) lgt[i] = labels[b * GG * 5 + i];
    __syncthreads();

    // ---- phase 1: fg test + block-local compaction ----
    int a = blockIdx.x * 256 + tid;
    bool fg = false;
    if (a < AA) {
        float stv = st_[a];
        float xc = __fmul_rn(__fadd_rn(xs_[a], 0.5f), stv);
        float yc = __fmul_rn(__fadd_rn(ys_[a], 0.5f), stv);
        float rr = __fmul_rn(1.5f, stv);
        for (int g = 0; g < GG && !fg; g++)
            fg = dev_in(lgt[g * 5 + 1], lgt[g * 5 + 2], xc, yc, rr);
    }
    ull mk = __ballot(fg);
    int cw = __popcll(mk);
    int wbase = 0;
    if (ln == 0 && cw) wbase = atomicAdd(&scnt[0], cw);
    wbase = __shfl(wbase, 0, 64);
    if (fg) lloc[wbase + __popcll(mk & ((1ull << ln) - 1ull))] = a;
    __syncthreads();
    if (tid == 0) scnt[1] = atomicAdd(&cnt[b], scnt[0]);
    __syncthreads();
    int m = scnt[0], base = scnt[1];

    // ---- phase 2: syncless, 4 lanes per row, 16 rows per wave per pass ----
    int g16 = ln >> 2;                 // row group within wave (0..15)
    int q   = ln & 3;                  // class-quarter
    int lb  = ln & ~3;                 // group base lane for ordered shfl combine

    for (int p = 0; p * 64 + w * 16 < m; p++) {
        int j = p * 64 + w * 16 + g16;
        bool valid = j < m;
        int aa = valid ? lloc[j] : 0;
        const float* src = outputs + ((size_t)b * AA + aa) * NO;

        float obj = 0.0f, s1 = 0.0f, s2 = 0.0f;
        if (valid) {
            obj = src[4];
            int c0 = q * 20;
#pragma unroll 4
            for (int jj = 0; jj < 20; jj++) {
                float x = src[5 + c0 + jj];
                float mm = __fmul_rn(x, obj);
                float pp = __fsqrt_rn(mm);
                s1 += __logf(__fsub_rn(1.0f, pp));                      // log1p(-p)
                s2 += softplus_bce(x);                                  // cls BCE base
            }
        }
        // left-to-right combine == old red2[0]+red2[1]+red2[2]+red2[3] (bitwise)
        float s1t = __shfl(s1, lb + 0, 64) + __shfl(s1, lb + 1, 64)
                  + __shfl(s1, lb + 2, 64) + __shfl(s1, lb + 3, 64);
        float s2t = __shfl(s2, lb + 0, 64) + __shfl(s2, lb + 1, 64)
                  + __shfl(s2, lb + 2, 64) + __shfl(s2, lb + 3, 64);

        if (valid && q == 0) {
            int i = base + j;
            if (i < CAP) {
                float nsl = -s1t;
                float stv2 = st_[aa];
                float xc2 = __fmul_rn(__fadd_rn(xs_[aa], 0.5f), stv2);
                float yc2 = __fmul_rn(__fadd_rn(ys_[aa], 0.5f), stv2);
                float r2  = __fmul_rn(1.5f, stv2);
                alist[b * CAP + i] = aa;
                blist[b * CAP + i] = make_float4(src[0], src[1], src[2], src[3]);
                glist[b * CAP + i] = make_float4(xc2, yc2, r2, stv2);
                misc[b * CAP + i]  = make_float4(s2t, obj, nsl, 0.0f);
            }
        }
    }
}

// =====================================================================
// K2: SimOTA top-10 assignment — 2 waves per (b,g) pair, deterministic
// 20-candidate rank merge. Class cost computed ON THE FLY (cls_ct) from
// the anchor's class-gc logit — bitwise identical to the old clsterm read.
// =====================================================================
__global__ __launch_bounds__(256) void k2_assign(
    const float* __restrict__ outputs, const float* __restrict__ labels,
    int* __restrict__ ctrl,
    const int* __restrict__ alist,
    const float4* __restrict__ blist, const float4* __restrict__ glist,
    const float4* __restrict__ misc,
    int* __restrict__ matchcnt, int2* __restrict__ wl)
{
    __shared__ ull   skey[2][20];
    __shared__ float sval[2][20];

    int w = threadIdx.x >> 6, ln = threadIdx.x & 63;
    int pairLocal = w >> 1;            // 0..1 : two pairs per block
    int half = w & 1;                  // 0..1 : two waves per pair
    int pair = blockIdx.x * 2 + pairLocal;   // < BB*GG = 1280
    int b = pair / GG, g = pair - b * GG;
    int* cnt   = ctrl + 8;
    int* wlcnt = ctrl + 40;

    const float* L = labels + (b * GG + g) * 5;
    int   gc = (int)L[0];
    float gx = L[1], gy = L[2], gw = L[3], gh = L[4];
    int n = cnt[b]; n = n > CAP ? CAP : n;

    const float4* bp  = blist + b * CAP;
    const float4* gp  = glist + b * CAP;
    const float4* mp  = misc  + b * CAP;
    const int*    ap  = alist + b * CAP;
    const float*  ob  = outputs + (size_t)b * AA * NO;

    ull t[10]; float tv[10];
#pragma unroll
    for (int k = 0; k < 10; k++) { t[k] = U64MAX; tv[k] = 0.0f; }

    for (int i = ln + half * 64; i < n; i += 128) {
        int aa = ap[i];
        float4 pb = bp[i];
        float4 gm = gp[i];
        float4 mo = mp[i];                         // (s2t, obj, nsl, -)
        float x = ob[(size_t)aa * NO + 5 + gc];    // class-gc logit (L2-warm gather)
        float ct = cls_ct(x, mo.y, mo.z);
        float2 ci = cost_iou(gx, gy, gw, gh, pb.x, pb.y, pb.z, pb.w,
                             gm.x, gm.y, gm.z, ct, 1.0f);
        unsigned u = __float_as_uint(ci.x);
        u ^= (u & 0x80000000u) ? 0xFFFFFFFFu : 0x80000000u;
        ull key = ((ull)u << 32) | (unsigned)((aa << 11) | i);
        if (key < t[9]) {
            int p = 0;
#pragma unroll
            for (int k = 0; k < 10; k++) p += (t[k] < key) ? 1 : 0;
#pragma unroll
            for (int k = 9; k >= 1; k--) t[k] = (k > p) ? t[k - 1] : t[k];
#pragma unroll
            for (int k = 0; k < 10; k++) if (k == p) t[k] = key;
        }
        float v = ci.y;
        if (v > tv[9]) {
            int p = 0;
#pragma unroll
            for (int k = 0; k < 10; k++) p += (tv[k] > v) ? 1 : 0;
#pragma unroll
            for (int k = 9; k >= 1; k--) tv[k] = (k > p) ? tv[k - 1] : tv[k];
#pragma unroll
            for (int k = 0; k < 10; k++) if (k == p) tv[k] = v;
        }
    }

    // per-wave sorted extraction
    ull mykey = U64MAX; float myv = 0.0f;
#pragma unroll
    for (int r = 0; r < 10; r++) {
        ull mn = wave_min_u64(t[0]);
        if (ln == r) mykey = mn;
        bool own = (t[0] == mn);
#pragma unroll
        for (int k = 0; k < 9; k++) t[k] = own ? t[k + 1] : t[k];
        t[9] = own ? U64MAX : t[9];
    }
#pragma unroll
    for (int r = 0; r < 10; r++) {
        float mv = wave_max_f(tv[0]);
        if (ln == r) myv = mv;
        ull bal = __ballot(tv[0] == mv);
        int first = (int)__ffsll((long long)bal) - 1;
        bool own = (ln == first);
#pragma unroll
        for (int k = 0; k < 9; k++) tv[k] = own ? tv[k + 1] : tv[k];
        tv[9] = own ? 0.0f : tv[9];
    }

    if (ln < 10) { skey[pairLocal][half * 10 + ln] = mykey; sval[pairLocal][half * 10 + ln] = myv; }
    __syncthreads();

    // deterministic 20-candidate merge (half 0 commits)
    ull  kc = (ln < 20) ? skey[pairLocal][ln] : U64MAX;
    float vc = (ln < 20) ? sval[pairLocal][ln] : -1.0f;

    int krank = 0, vrank = 0;
#pragma unroll
    for (int j = 0; j < 20; j++) {
        ull kj = (ull)__shfl((long long)kc, j, 64);
        float vj = __shfl(vc, j, 64);
        krank += (kj < kc) ? 1 : 0;                                // keys distinct
        vrank += ((vj > vc) || (vj == vc && j < ln)) ? 1 : 0;      // stable by index
    }

    ull mykey2 = U64MAX;
    float isum = 0.0f;
#pragma unroll
    for (int r = 0; r < 10; r++) {
        ull balk = __ballot(ln < 20 && krank == r);
        int srck = (int)__ffsll((long long)balk) - 1;
        ull kr = (ull)__shfl((long long)kc, srck, 64);
        if (ln == r && srck >= 0) mykey2 = kr;

        ull balv = __ballot(ln < 20 && vrank == r);
        int srcv = (int)__ffsll((long long)balv) - 1;
        float vr = __shfl(vc, srcv, 64);
        isum += (srcv >= 0) ? vr : 0.0f;                           // descending order sum
    }

    int dk = (int)isum;
    dk = dk < 1 ? 1 : (dk > 10 ? 10 : dk);
    if (half == 0 && ln < dk && mykey2 != U64MAX) {
        unsigned low = (unsigned)mykey2;
        int a = (int)(low >> 11);
        int i2 = (int)(low & 2047);
        int idx = b * AA + a;
        if (atomicAdd(&matchcnt[idx], 1) == 0) {
            int wp = atomicAdd(wlcnt, 1);
            if (wp < CAPW) wl[wp] = make_int2(idx, (g << 16) | i2);
        }
    }
}

// =====================================================================
// K4: worklist loss + grid-stride all-anchor obj-BCE (MLP-batched loads)
// + ticket finalize. Multi-match argmin recomputes ct on the fly (cls_ct,
// bitwise-identical). The mg-path's cost is discarded (only iou used) so
// ct=0 there — pred_iou is ct-independent, bitwise unchanged.
// =====================================================================
__global__ __launch_bounds__(256) void k4_loss(
    const float* __restrict__ outputs, const float* __restrict__ origin,
    const float* __restrict__ labels,
    const float* __restrict__ xs_, const float* __restrict__ ys_, const float* __restrict__ st_,
    const float4* __restrict__ blist, const float4* __restrict__ glist,
    const float4* __restrict__ misc,
    const int* __restrict__ matchcnt,
    const int2* __restrict__ wl, int* __restrict__ ctrl,
    float* __restrict__ out)
{
    float* acc = (float*)ctrl;
    int* wlcnt = ctrl + 40;
    int* fin   = ctrl + 41;

    int tid = threadIdx.x;
    int gid = blockIdx.x * 256 + tid;
    int nw = *wlcnt; nw = nw > CAPW ? CAPW : nw;

    float t_fg = 0.0f, t_iou = 0.0f, t_obj = 0.0f, t_cls = 0.0f, t_l1 = 0.0f;

    {
        const int STR = K4GRID * 256;    // 26624
        float xv[11];
        int kmax = 0;
#pragma unroll
        for (int k = 0; k < 11; k++) {
            int idx = gid + k * STR;
            if (idx < BB * AA) { xv[k] = outputs[(size_t)idx * NO + 4]; kmax = k + 1; }
        }
#pragma unroll
        for (int k = 0; k < 11; k++)
            if (k < kmax) t_obj += softplus_bce(xv[k]);
    }

    if (gid < nw) {
        int2 e = wl[gid];
        int idx = e.x;
        int b = idx / AA;
        int a = idx - b * AA;
        int ci = e.y & 0xFFFF;
        int g1 = e.y >> 16;
        int mcnt = matchcnt[idx];

        float4 pb = blist[b * CAP + ci];
        float4 gm = glist[b * CAP + ci];
        float4 mo = misc[b * CAP + ci];    // (s2t, obj, nsl, -)
        const float* Lb = labels + b * GG * 5;
        const float* row = outputs + (size_t)idx * NO;

        int mg;
        if (mcnt == 1) {
            mg = g1;
        } else {
            mg = 0; float best = FLT_MAX;
            for (int g = 0; g < GG; g++) {
                int gc = (int)Lb[g * 5];
                float ct = cls_ct(row[5 + gc], mo.y, mo.z);
                float2 r = cost_iou(Lb[g * 5 + 1], Lb[g * 5 + 2], Lb[g * 5 + 3], Lb[g * 5 + 4],
                                    pb.x, pb.y, pb.z, pb.w, gm.x, gm.y, gm.z, ct, 1.0f);
                if (r.x < best) { best = r.x; mg = g; }
            }
        }
        t_fg = 1.0f;
        t_obj += -mo.y;   // BCE(x,1)-BCE(x,0)
        float gx = Lb[mg * 5 + 1], gy = Lb[mg * 5 + 2], gw = Lb[mg * 5 + 3], gh = Lb[mg * 5 + 4];
        int mcls = (int)Lb[mg * 5];
        // old code fed clsterm into cost_iou here but only used r.y (iou), which is
        // ct-independent -> pass 0.0f, bitwise-identical pred_iou.
        float2 r = cost_iou(gx, gy, gw, gh, pb.x, pb.y, pb.z, pb.w, gm.x, gm.y, gm.z, 0.0f, 1.0f);
        float pred_iou = r.y;
        float tlx = fmaxf(pb.x - pb.z * 0.5f, gx - gw * 0.5f);
        float tly = fmaxf(pb.y - pb.w * 0.5f, gy - gh * 0.5f);
        float brx = fminf(pb.x + pb.z * 0.5f, gx + gw * 0.5f);
        float bry = fminf(pb.y + pb.w * 0.5f, gy + gh * 0.5f);
        float en = (tlx < brx && tly < bry) ? 1.0f : 0.0f;
        float ai = (brx - tlx) * (bry - tly) * en;
        float iou = ai / (pb.z * pb.w + gw * gh - ai + 1e-16f);
        t_iou = 1.0f - iou * iou;
        const float* op = origin + (size_t)idx * 4;
        float stv = st_[a], xsv = xs_[a], ysv = ys_[a];
        t_l1 = fabsf(op[0] - (gx / stv - xsv)) + fabsf(op[1] - (gy / stv - ysv))
             + fabsf(op[2] - logf(gw / stv + 1e-8f)) + fabsf(op[3] - logf(gh / stv + 1e-8f));
        t_cls = mo.x - row[5 + mcls] * pred_iou;
    }

    t_fg = wave_sum(t_fg); t_iou = wave_sum(t_iou); t_obj = wave_sum(t_obj);
    t_cls = wave_sum(t_cls); t_l1 = wave_sum(t_l1);
    __shared__ float red[5][4];
    int wv = threadIdx.x >> 6, ln = threadIdx.x & 63;
    if (ln == 0) { red[0][wv] = t_fg; red[1][wv] = t_iou; red[2][wv] = t_obj; red[3][wv] = t_cls; red[4][wv] = t_l1; }
    __syncthreads();
    if (threadIdx.x == 0) {
        atomicAdd(&acc[0], red[0][0] + red[0][1] + red[0][2] + red[0][3]);
        atomicAdd(&acc[1], red[1][0] + red[1][1] + red[1][2] + red[1][3]);
        atomicAdd(&acc[2], red[2][0] + red[2][1] + red[2][2] + red[2][3]);
        atomicAdd(&acc[3], red[3][0] + red[3][1] + red[3][2] + red[3][3]);
        atomicAdd(&acc[4], red[4][0] + red[4][1] + red[4][2] + red[4][3]);
        __threadfence();
        int tkt = atomicAdd(fin, 1);
        if (tkt == (int)gridDim.x - 1) {
            float a0 = atomicAdd(&acc[0], 0.0f);
            float a1 = atomicAdd(&acc[1], 0.0f);
            float a2 = atomicAdd(&acc[2], 0.0f);
            float a3 = atomicAdd(&acc[3], 0.0f);
            float a4 = atomicAdd(&acc[4], 0.0f);
            float nfg = fmaxf(a0, 1.0f);
            float li = 5.0f * a1 / nfg;
            float lo = a2 / nfg;
            float lc = a3 / nfg;
            float ll = a4 / nfg;
            out[0] = li + lo + lc + ll;
            out[1] = li;
            out[2] = lo;
            out[3] = lc;
            out[4] = ll;
            out[5] = nfg / (float)(BB * GG);
        }
    }
}

// ---------- workspace layout (16B-aligned blocks; clsterm ELIMINATED) ----------
static constexpr size_t NBA       = (size_t)BB * AA;                 // 268800
static constexpr size_t OFF_MC    = 512;                             // ctrl first
static constexpr size_t OFF_ALIST = OFF_MC + NBA * 4;
static constexpr size_t OFF_BL    = OFF_ALIST + (size_t)BB * CAP * 4;
static constexpr size_t OFF_GL    = OFF_BL + (size_t)BB * CAP * 16;
static constexpr size_t OFF_MISC  = OFF_GL + (size_t)BB * CAP * 16;
static constexpr size_t OFF_WL    = OFF_MISC + (size_t)BB * CAP * 16;
// total = OFF_WL + CAPW*8 ≈ 4.5 MB

extern "C" void kernel_launch(void* const* d_in, const int* in_sizes, int n_in,
                              void* d_out, int out_size, void* d_ws, size_t ws_size,
                              hipStream_t stream)
{
    (void)in_sizes; (void)n_in; (void)out_size; (void)ws_size;
    const float* outputs = (const float*)d_in[0];
    const float* origin  = (const float*)d_in[1];
    const float* labels  = (const float*)d_in[2];
    const float* xs_     = (const float*)d_in[3];
    const float* ys_     = (const float*)d_in[4];
    const float* st_     = (const float*)d_in[5];
    float* out = (float*)d_out;
    char* ws = (char*)d_ws;

    int*    ctrl     = (int*)(ws);
    int*    matchcnt = (int*)(ws + OFF_MC);
    int*    alist    = (int*)(ws + OFF_ALIST);
    float4* blist    = (float4*)(ws + OFF_BL);
    float4* glist    = (float4*)(ws + OFF_GL);
    float4* misc     = (float4*)(ws + OFF_MISC);
    int2*   wl       = (int2*)(ws + OFF_WL);

    // K1: syncless fg-compaction + per-anchor term kernel (no clsterm)
    dim3 grid1((AA + 255) / 256, BB);   // 33 x 32
    k1_fgcls<<<grid1, 256, 0, stream>>>(outputs, labels, xs_, ys_, st_,
                                        ctrl, matchcnt, alist,
                                        blist, glist, misc);

    // K2: 2 waves per (b,g) pair -> 640 blocks; on-the-fly class cost
    k2_assign<<<BB * GG / 2, 256, 0, stream>>>(outputs, labels, ctrl, alist,
                                               blist, glist, misc,
                                               matchcnt, wl);

    // K4: unchanged partition (K4GRID=104), MLP-batched obj gather
    k4_loss<<<K4GRID, 256, 0, stream>>>(outputs, origin, labels, xs_, ys_, st_,
                                        blist, glist, misc, matchcnt, wl,
                                        ctrl, out);
}